// Round 1
// baseline (1483.482 us; speedup 1.0000x reference)
//
#include <hip/hip_runtime.h>
#include <math.h>

#define D 128
#define B 8
#define T_SAMP 32768
#define K 512
#define NT 8
#define NFRM 128
#define TB 8
#define HSTR 68

// ws layout (float offsets)
#define WS_C1   0
#define WS_ENV8 1024
#define WS_SEL  2048
#define WS_VAL  6144

__device__ __forceinline__ float lrelu(float v){ return v >= 0.0f ? v : 0.2f*v; }

// out[b][n] = act(bias[n] + sum_j in[b][j]*w[j*D+n]); n = tid&127, 4 batches per thread
__device__ void layer128(const float* __restrict__ in, const float* __restrict__ w,
                         const float* __restrict__ bias, float* __restrict__ outp,
                         int tid, int mode /*0=lrelu,1=abs,2=none*/)
{
    int n = tid & 127, bg = tid >> 7;
    const float* i0 = in + (bg*4+0)*D;
    const float* i1 = in + (bg*4+1)*D;
    const float* i2 = in + (bg*4+2)*D;
    const float* i3 = in + (bg*4+3)*D;
    float bb = bias[n];
    float a0=bb,a1=bb,a2=bb,a3=bb;
    for (int j=0;j<D;j++){
        float wv = w[j*D+n];
        a0 = fmaf(i0[j], wv, a0);
        a1 = fmaf(i1[j], wv, a1);
        a2 = fmaf(i2[j], wv, a2);
        a3 = fmaf(i3[j], wv, a3);
    }
    if (mode==0){ a0=lrelu(a0);a1=lrelu(a1);a2=lrelu(a2);a3=lrelu(a3); }
    else if (mode==1){ a0=fabsf(a0);a1=fabsf(a1);a2=fabsf(a2);a3=fabsf(a3); }
    outp[(bg*4+0)*D+n]=a0;
    outp[(bg*4+1)*D+n]=a1;
    outp[(bg*4+2)*D+n]=a2;
    outp[(bg*4+3)*D+n]=a3;
}

__global__ __launch_bounds__(256) void prep_kernel(
    const float* __restrict__ x, const float* __restrict__ wt,
    const float* __restrict__ tc_w1, const float* __restrict__ tc_b1,
    const float* __restrict__ tc_w2, const float* __restrict__ tc_b2,
    const float* __restrict__ tc_w3, const float* __restrict__ tc_b3,
    const float* __restrict__ env_w1, const float* __restrict__ env_b1,
    const float* __restrict__ env_w2, const float* __restrict__ env_b2,
    const float* __restrict__ env_w3, const float* __restrict__ env_b3,
    const float* __restrict__ sk_w1, const float* __restrict__ sk_b1,
    float* __restrict__ ws)
{
    __shared__ float xl[B*D], buf1[B*D], buf2[B*D];
    __shared__ float lgts[B*NT], pmax[NT*8], mxr[NT];
    __shared__ int idxl[B];
    int tid = threadIdx.x;
    for (int i=tid;i<B*D;i+=256) xl[i]=x[i];
    __syncthreads();
    layer128(xl, tc_w1, tc_b1, buf1, tid, 0);
    __syncthreads();
    layer128(buf1, tc_w2, tc_b2, buf2, tid, 0);
    __syncthreads();
    if (tid < 64){
        int b = tid>>3, n = tid&7;
        float a = tc_b3[n];
        for (int j=0;j<D;j++) a = fmaf(buf2[b*D+j], tc_w3[j*NT+n], a);
        lgts[b*NT+n] = a;
    } else if (tid < 128){
        int r = (tid-64)>>3, p = tid&7;
        float m = -1e30f;
        for (int k=p*64;k<p*64+64;k++) m = fmaxf(m, wt[r*K+k]);
        pmax[r*8+p] = m;
    }
    __syncthreads();
    if (tid < 8){
        int b = tid; float m = -1e30f; int idx = 0;
        for (int n=0;n<NT;n++){ float v = lgts[b*NT+n]; if (v > m){ m=v; idx=n; } }
        float S = 0.f;
        for (int n=0;n<NT;n++) S += expf(lgts[b*NT+n]-m);
        ws[WS_VAL+b] = 1.0f/S;   // max of softmax = exp(0)/S
        idxl[b] = idx;
    } else if (tid < 16){
        int r = tid-8; float m = -1e30f;
        for (int p=0;p<8;p++) m = fmaxf(m, pmax[r*8+p]);
        mxr[r] = m;
    }
    __syncthreads();
    for (int o=tid;o<B*K;o+=256){
        int b = o>>9, k = o&(K-1);
        int id = idxl[b];
        ws[WS_SEL+o] = wt[id*K+k] / (mxr[id] + 1e-8f);
    }
    layer128(xl, env_w1, env_b1, buf1, tid, 0);
    __syncthreads();
    layer128(buf1, env_w2, env_b2, buf2, tid, 0);
    __syncthreads();
    layer128(buf2, env_w3, env_b3, ws+WS_ENV8, tid, 1);
    layer128(xl, sk_w1, sk_b1, ws+WS_C1, tid, 2);
}

__global__ __launch_bounds__(512) void synth_kernel(
    const float* __restrict__ pos_w1, const float* __restrict__ pos_b1,
    const float* __restrict__ pos_w2, const float* __restrict__ pos_b2,
    const float* __restrict__ pos_w3, const float* __restrict__ pos_b3,
    const float* __restrict__ sk_w1,
    const float* __restrict__ sk_w2, const float* __restrict__ sk_b2,
    const float* __restrict__ sk_w3, const float* __restrict__ sk_b3,
    const float* __restrict__ ws, float* __restrict__ out)
{
    __shared__ __align__(16) float wbuf[D*D];      // 64KB: staged weight
    __shared__ __align__(16) float h1T[D*HSTR];    // h1 transposed [j][r], padded stride
    __shared__ __align__(16) float h2T[D*HSTR];
    __shared__ __align__(16) float peT[33*9];
    __shared__ __align__(16) float sA[D*9];        // g1T then PT
    __shared__ __align__(16) float sB[D*9];        // g2T then a1T
    __shared__ __align__(16) float c1l[B*D];

    int tid = threadIdx.x;
    int t0 = blockIdx.x * TB;

    for (int i=tid;i<B*D;i+=512) c1l[i] = ws[WS_C1+i];
    for (int i=tid;i<33*D;i+=512) wbuf[i] = pos_w1[i];
    for (int i=tid;i<33*TB;i+=512){
        int j = i>>3, r = i&7;
        float pf = (float)(-1.0 + 2.0*(double)(t0+r)/32767.0);
        float v;
        if (j == 0) v = pf;
        else if (j <= 16) v = sinf(pf * ((float)M_PI * (float)(1<<(j-1))));
        else v = cosf(pf * ((float)M_PI * (float)(1<<(j-17))));
        peT[j*9+r] = v;
    }
    __syncthreads();

    const int c  = tid & 127;
    const int rg = tid >> 7;          // 0..3

    // P1: g1 = lrelu(pe@pw1+pb1), rows rg*2..rg*2+1 -> sA (g1T)
    {
        int r0 = rg*2;
        float a0 = pos_b1[c], a1 = a0;
        for (int j=0;j<33;j++){
            float w = wbuf[j*D+c];
            a0 = fmaf(peT[j*9+r0],   w, a0);
            a1 = fmaf(peT[j*9+r0+1], w, a1);
        }
        sA[c*9+r0]   = lrelu(a0);
        sA[c*9+r0+1] = lrelu(a1);
    }
    __syncthreads();
    for (int i=tid;i<D*D;i+=512) wbuf[i] = pos_w2[i];
    __syncthreads();
    // P2: g2 -> sB
    {
        int r0 = rg*2;
        float a0 = pos_b2[c], a1 = a0;
        #pragma unroll 4
        for (int j=0;j<D;j++){
            float w = wbuf[j*D+c];
            a0 = fmaf(sA[j*9+r0],   w, a0);
            a1 = fmaf(sA[j*9+r0+1], w, a1);
        }
        sB[c*9+r0]   = lrelu(a0);
        sB[c*9+r0+1] = lrelu(a1);
    }
    __syncthreads();
    for (int i=tid;i<D*D;i+=512) wbuf[i] = pos_w3[i];
    __syncthreads();
    // P3: P = g2@pw3+pb3 -> sA (overwrite g1T)
    {
        int r0 = rg*2;
        float a0 = pos_b3[c], a1 = a0;
        #pragma unroll 4
        for (int j=0;j<D;j++){
            float w = wbuf[j*D+c];
            a0 = fmaf(sB[j*9+r0],   w, a0);
            a1 = fmaf(sB[j*9+r0+1], w, a1);
        }
        sA[c*9+r0]   = a0;
        sA[c*9+r0+1] = a1;
    }
    __syncthreads();
    for (int i=tid;i<D*D;i+=512) wbuf[i] = sk_w1[i];
    __syncthreads();
    // P4: A1 = P@sk_w1 (no bias) -> sB (overwrite g2T)
    {
        int r0 = rg*2;
        float a0 = 0.f, a1 = 0.f;
        #pragma unroll 4
        for (int j=0;j<D;j++){
            float w = wbuf[j*D+c];
            a0 = fmaf(sA[j*9+r0],   w, a0);
            a1 = fmaf(sA[j*9+r0+1], w, a1);
        }
        sB[c*9+r0]   = a0;
        sB[c*9+r0+1] = a1;
    }
    __syncthreads();
    // P5: h1T[j][r] = lrelu(A1[ti][j] + c1[b][j]), r = b*8+ti
    {
        int r0 = rg*16;
        for (int r=r0;r<r0+16;r++){
            int b = r>>3, ti = r&7;
            h1T[c*HSTR + r] = lrelu(sB[c*9+ti] + c1l[b*D+c]);
        }
    }
    __syncthreads();
    for (int i=tid;i<D*D;i+=512) wbuf[i] = sk_w2[i];
    __syncthreads();
    // P6: h2 = lrelu(h1@sw2+sb2); thread: col c, rows rg*16..+16
    {
        int r0 = rg*16;
        float acc[16];
        float bv = sk_b2[c];
        #pragma unroll
        for (int i=0;i<16;i++) acc[i]=bv;
        #pragma unroll 2
        for (int j=0;j<D;j++){
            float w = wbuf[j*D+c];
            const float4* hp = (const float4*)&h1T[j*HSTR + r0];
            #pragma unroll
            for (int q=0;q<4;q++){
                float4 h4 = hp[q];
                acc[4*q+0] = fmaf(h4.x, w, acc[4*q+0]);
                acc[4*q+1] = fmaf(h4.y, w, acc[4*q+1]);
                acc[4*q+2] = fmaf(h4.z, w, acc[4*q+2]);
                acc[4*q+3] = fmaf(h4.w, w, acc[4*q+3]);
            }
        }
        #pragma unroll
        for (int i=0;i<16;i++) h2T[c*HSTR + r0 + i] = lrelu(acc[i]);
    }
    __syncthreads();
    // P7: layer3 over 8 k-tiles of 64 cols, fused exp + sel-dot accumulation
    const int kc = tid & 63;
    const int wv = tid >> 6;          // wave id == batch b, rows wv*8..+8
    float S[8], W[8];
    #pragma unroll
    for (int i=0;i<8;i++){ S[i]=0.f; W[i]=0.f; }
    for (int kt=0;kt<8;kt++){
        for (int i=tid;i<D*64;i+=512){
            int j = i>>6, k2 = i&63;
            wbuf[i] = sk_w3[j*K + kt*64 + k2];
        }
        __syncthreads();
        float acc[8];
        float bv = sk_b3[kt*64+kc];
        #pragma unroll
        for (int i=0;i<8;i++) acc[i]=bv;
        #pragma unroll 2
        for (int j=0;j<D;j++){
            float w = wbuf[j*64+kc];
            const float4* hp = (const float4*)&h2T[j*HSTR + wv*8];
            #pragma unroll
            for (int q=0;q<2;q++){
                float4 h4 = hp[q];
                acc[4*q+0] = fmaf(h4.x, w, acc[4*q+0]);
                acc[4*q+1] = fmaf(h4.y, w, acc[4*q+1]);
                acc[4*q+2] = fmaf(h4.z, w, acc[4*q+2]);
                acc[4*q+3] = fmaf(h4.w, w, acc[4*q+3]);
            }
        }
        float selv = ws[WS_SEL + wv*K + kt*64 + kc];
        #pragma unroll
        for (int i=0;i<8;i++){
            float e = expf(acc[i]);
            S[i] += e;
            W[i] = fmaf(e, selv, W[i]);
        }
        __syncthreads();
    }
    // P8: butterfly reduce over 64 lanes, epilogue
    #pragma unroll
    for (int i=0;i<8;i++){
        #pragma unroll
        for (int off=32; off>0; off>>=1){
            S[i] += __shfl_xor(S[i], off, 64);
            W[i] += __shfl_xor(W[i], off, 64);
        }
    }
    int lane = tid & 63;
    if (lane < 8){
        int i = lane;
        int t = t0 + i;
        float coord = (t + 0.5f)*(1.0f/256.0f) - 0.5f;
        float fi = floorf(coord);
        float frac = coord - fi;
        int i0 = (int)fi;
        int i1 = i0 + 1;
        i0 = min(max(i0,0),NFRM-1);
        i1 = min(max(i1,0),NFRM-1);
        float e0 = ws[WS_ENV8 + wv*NFRM + i0];
        float e1 = ws[WS_ENV8 + wv*NFRM + i1];
        float envv = e0*(1.0f-frac) + e1*frac;
        out[wv*T_SAMP + t] = (W[i]/S[i]) * envv * ws[WS_VAL+wv];
    }
}

extern "C" void kernel_launch(void* const* d_in, const int* in_sizes, int n_in,
                              void* d_out, int out_size, void* d_ws, size_t ws_size,
                              hipStream_t stream)
{
    (void)in_sizes; (void)n_in; (void)out_size; (void)ws_size;
    const float* x       = (const float*)d_in[0];
    const float* wt      = (const float*)d_in[1];
    const float* tc_w1   = (const float*)d_in[2];
    const float* tc_b1   = (const float*)d_in[3];
    const float* tc_w2   = (const float*)d_in[4];
    const float* tc_b2   = (const float*)d_in[5];
    const float* tc_w3   = (const float*)d_in[6];
    const float* tc_b3   = (const float*)d_in[7];
    const float* env_w1  = (const float*)d_in[8];
    const float* env_b1  = (const float*)d_in[9];
    const float* env_w2  = (const float*)d_in[10];
    const float* env_b2  = (const float*)d_in[11];
    const float* env_w3  = (const float*)d_in[12];
    const float* env_b3  = (const float*)d_in[13];
    const float* pos_w1  = (const float*)d_in[14];
    const float* pos_b1  = (const float*)d_in[15];
    const float* pos_w2  = (const float*)d_in[16];
    const float* pos_b2  = (const float*)d_in[17];
    const float* pos_w3  = (const float*)d_in[18];
    const float* pos_b3  = (const float*)d_in[19];
    const float* sk_w1   = (const float*)d_in[20];
    const float* sk_b1   = (const float*)d_in[21];
    const float* sk_w2   = (const float*)d_in[22];
    const float* sk_b2   = (const float*)d_in[23];
    const float* sk_w3   = (const float*)d_in[24];
    const float* sk_b3   = (const float*)d_in[25];
    float* ws  = (float*)d_ws;
    float* out = (float*)d_out;

    hipLaunchKernelGGL(prep_kernel, dim3(1), dim3(256), 0, stream,
        x, wt, tc_w1, tc_b1, tc_w2, tc_b2, tc_w3, tc_b3,
        env_w1, env_b1, env_w2, env_b2, env_w3, env_b3,
        sk_w1, sk_b1, ws);
    hipLaunchKernelGGL(synth_kernel, dim3(T_SAMP/TB), dim3(512), 0, stream,
        pos_w1, pos_b1, pos_w2, pos_b2, pos_w3, pos_b3,
        sk_w1, sk_w2, sk_b2, sk_w3, sk_b3, ws, out);
}

// Round 2
// 123.511 us; speedup vs baseline: 12.0109x; 12.0109x over previous
//
#include <hip/hip_runtime.h>
#include <math.h>

#define D 128
#define B 8
#define T_SAMP 32768
#define K 512
#define NT 8
#define NFRM 128

// fallback tile
#define TB 8
#define HSTR 68

// ws float-region layout
#define WS_C1   0
#define WS_ENV8 1024
#define WS_SEL  2048
#define WS_VAL  6144
// bf16 transposed-weight region
#define WSBF_BYTE 32768
#define OP1 0        // pw1T [128][72]
#define OP2 9216     // pw2T [128][136]
#define OP3 26624    // pw3T
#define OS1 44032    // skw1T
#define OS2 61440    // skw2T
#define OS3 78848    // skw3T [512][136]
#define WTOT 148480
#define WS_NEED (WSBF_BYTE + WTOT*2)

typedef __attribute__((ext_vector_type(8))) short short8;
typedef __attribute__((ext_vector_type(4))) float f32x4;

__device__ __forceinline__ float lrelu(float v){ return v >= 0.0f ? v : 0.2f*v; }

__device__ __forceinline__ unsigned pk2(float lo, float hi){
    unsigned a = __builtin_bit_cast(unsigned, lo); a += 0x7fffu + ((a>>16)&1u);
    unsigned b = __builtin_bit_cast(unsigned, hi); b += 0x7fffu + ((b>>16)&1u);
    return (a>>16) | (b & 0xffff0000u);
}
__device__ __forceinline__ unsigned short bfr(float f){
    unsigned u = __builtin_bit_cast(unsigned, f); u += 0x7fffu + ((u>>16)&1u);
    return (unsigned short)(u>>16);
}
__device__ __forceinline__ float bf2f(short s){
    unsigned u = ((unsigned)(unsigned short)s) << 16;
    return __builtin_bit_cast(float, u);
}

#define VMCNT0 asm volatile("s_waitcnt vmcnt(0)" ::: "memory")

// ---------------- prep helper (fp32, tiny) ----------------
__device__ void layer128(const float* __restrict__ in, const float* __restrict__ w,
                         const float* __restrict__ bias, float* __restrict__ outp,
                         int tid, int mode)
{
    int n = tid & 127, bg = tid >> 7;
    const float* i0 = in + (bg*4+0)*D;
    const float* i1 = in + (bg*4+1)*D;
    const float* i2 = in + (bg*4+2)*D;
    const float* i3 = in + (bg*4+3)*D;
    float bb = bias[n];
    float a0=bb,a1=bb,a2=bb,a3=bb;
    for (int j=0;j<D;j++){
        float wv = w[j*D+n];
        a0 = fmaf(i0[j], wv, a0);
        a1 = fmaf(i1[j], wv, a1);
        a2 = fmaf(i2[j], wv, a2);
        a3 = fmaf(i3[j], wv, a3);
    }
    if (mode==0){ a0=lrelu(a0);a1=lrelu(a1);a2=lrelu(a2);a3=lrelu(a3); }
    else if (mode==1){ a0=fabsf(a0);a1=fabsf(a1);a2=fabsf(a2);a3=fabsf(a3); }
    outp[(bg*4+0)*D+n]=a0;
    outp[(bg*4+1)*D+n]=a1;
    outp[(bg*4+2)*D+n]=a2;
    outp[(bg*4+3)*D+n]=a3;
}

// block 0: prep (c1/env/sel/values). blocks 1..: transpose weights to bf16 k-contig padded.
__global__ __launch_bounds__(256) void setup_kernel(
    const float* __restrict__ x, const float* __restrict__ wt,
    const float* __restrict__ tc_w1, const float* __restrict__ tc_b1,
    const float* __restrict__ tc_w2, const float* __restrict__ tc_b2,
    const float* __restrict__ tc_w3, const float* __restrict__ tc_b3,
    const float* __restrict__ env_w1, const float* __restrict__ env_b1,
    const float* __restrict__ env_w2, const float* __restrict__ env_b2,
    const float* __restrict__ env_w3, const float* __restrict__ env_b3,
    const float* __restrict__ sk_w1, const float* __restrict__ sk_b1,
    const float* __restrict__ pos_w1, const float* __restrict__ pos_w2,
    const float* __restrict__ pos_w3, const float* __restrict__ sk_w2,
    const float* __restrict__ sk_w3,
    float* __restrict__ ws)
{
    __shared__ float xl[B*D], buf1[B*D], buf2[B*D];
    __shared__ float lgts[B*NT], pmax[NT*8], mxr[NT];
    __shared__ int idxl[B];
    int tid = threadIdx.x;

    if (blockIdx.x != 0){
        int idx = (blockIdx.x - 1)*256 + tid;
        if (idx >= WTOT) return;
        unsigned short* wb = (unsigned short*)((char*)ws + WSBF_BYTE);
        float v;
        if (idx < OP2){
            int n = idx/72, k = idx%72;
            v = (k < 33) ? pos_w1[k*D + n] : 0.f;
        } else if (idx < OS3){
            int r = idx - OP2; int wsel = r/17408; int i = r%17408;
            int n = i/136, k = i%136;
            const float* W = wsel==0?pos_w2: wsel==1?pos_w3: wsel==2? sk_w1 : sk_w2;
            v = (k < 128) ? W[k*D + n] : 0.f;
        } else {
            int i = idx - OS3; int n = i/136, k = i%136;
            v = (k < 128) ? sk_w3[k*K + n] : 0.f;
        }
        wb[idx] = bfr(v);
        return;
    }

    for (int i=tid;i<B*D;i+=256) xl[i]=x[i];
    __syncthreads();
    layer128(xl, tc_w1, tc_b1, buf1, tid, 0);
    __syncthreads();
    layer128(buf1, tc_w2, tc_b2, buf2, tid, 0);
    __syncthreads();
    if (tid < 64){
        int b = tid>>3, n = tid&7;
        float a = tc_b3[n];
        for (int j=0;j<D;j++) a = fmaf(buf2[b*D+j], tc_w3[j*NT+n], a);
        lgts[b*NT+n] = a;
    } else if (tid < 128){
        int r = (tid-64)>>3, p = tid&7;
        float m = -1e30f;
        for (int k=p*64;k<p*64+64;k++) m = fmaxf(m, wt[r*K+k]);
        pmax[r*8+p] = m;
    }
    __syncthreads();
    if (tid < 8){
        int b = tid; float m = -1e30f; int idx = 0;
        for (int n=0;n<NT;n++){ float v = lgts[b*NT+n]; if (v > m){ m=v; idx=n; } }
        float S = 0.f;
        for (int n=0;n<NT;n++) S += expf(lgts[b*NT+n]-m);
        ws[WS_VAL+b] = 1.0f/S;
        idxl[b] = idx;
    } else if (tid < 16){
        int r = tid-8; float m = -1e30f;
        for (int p=0;p<8;p++) m = fmaxf(m, pmax[r*8+p]);
        mxr[r] = m;
    }
    __syncthreads();
    for (int o=tid;o<B*K;o+=256){
        int b = o>>9, k = o&(K-1);
        int id = idxl[b];
        ws[WS_SEL+o] = wt[id*K+k] / (mxr[id] + 1e-8f);
    }
    layer128(xl, env_w1, env_b1, buf1, tid, 0);
    __syncthreads();
    layer128(buf1, env_w2, env_b2, buf2, tid, 0);
    __syncthreads();
    layer128(buf2, env_w3, env_b3, ws+WS_ENV8, tid, 1);
    layer128(xl, sk_w1, sk_b1, ws+WS_C1, tid, 2);
}

// ---------------- MFMA synth ----------------
__global__ __launch_bounds__(512, 2) void synth_fast(
    const float* __restrict__ pos_b1, const float* __restrict__ pos_b2,
    const float* __restrict__ pos_b3, const float* __restrict__ sk_b2,
    const float* __restrict__ sk_b3,
    const float* __restrict__ ws, float* __restrict__ out)
{
    __shared__ __align__(16) unsigned char lds[149504];
    unsigned char* W0 = lds;                 // 34816
    unsigned char* W1 = lds + 34816;         // 34816
    unsigned char* ACT = lds + 69632;        // 69632 (phaseA bufs then h2)
    float* pebuf = (float*)ACT;              // [32][68] f32
    unsigned char* abuf0 = ACT + 8704;       // [32][136] bf16
    unsigned char* abuf1 = ACT + 17408;      // [32][136] bf16
    unsigned char* h2b  = ACT;               // [256][136] bf16 (phase B)
    float* C1f  = (float*)(lds + 139264);    // [1024]
    float* BIAf = (float*)(lds + 143360);    // [1024]
    float* PART = (float*)(lds + 147456);    // [512]

    const int tid = threadIdx.x;
    const int wv = tid >> 6, lane = tid & 63, lg = lane >> 4, lc = lane & 15;
    const int t0 = blockIdx.x * 32;
    const unsigned char* wg = (const unsigned char*)ws + WSBF_BYTE;
    const f32x4 z = {0.f,0.f,0.f,0.f};

    auto stage = [&](int elemoff, unsigned char* dst, int nbytes){
        const unsigned char* src = wg + (size_t)elemoff*2;
        for (int c = wv; c < (nbytes>>10); c += 8)
            __builtin_amdgcn_global_load_lds(
                (const __attribute__((address_space(1))) unsigned int*)(src + (c<<10) + lane*16),
                (__attribute__((address_space(3))) unsigned int*)(dst + (c<<10)), 16, 0, 0);
    };

    stage(OP1, W0, 18432);
    for (int i=tid;i<1024;i+=512) C1f[i] = ws[WS_C1+i];
    for (int i=tid;i<1024;i+=512){
        float v;
        if (i<128) v = pos_b1[i]; else if (i<256) v = pos_b2[i-128];
        else if (i<384) v = pos_b3[i-256]; else if (i<512) v = sk_b2[i-384];
        else v = sk_b3[i-512];
        BIAf[i] = v;
    }
    for (int i=tid;i<2048;i+=512){
        int r = i>>6, j = i&63;
        float v = 0.f;
        if (j < 33){
            float pf = (float)(-1.0 + 2.0*(double)(t0+r)/32767.0);
            if (j==0) v = pf;
            else if (j<=16) v = sinf(pf*((float)M_PI*(float)(1<<(j-1))));
            else v = cosf(pf*((float)M_PI*(float)(1<<(j-17))));
        }
        pebuf[r*68+j] = v;
    }
    VMCNT0; __syncthreads();

    // ---- g1 = lrelu(pe @ pw1 + b1), swapped orientation, K=64 ----
    stage(OP2, W1, 34816);
    {
        short8 aw[2]; f32x4 dd[2]; dd[0]=z; dd[1]=z;
        #pragma unroll
        for (int kt=0;kt<2;kt++)
            aw[kt] = *(const short8*)(W0 + ((16*wv+lc)*72 + 32*kt + 8*lg)*2);
        #pragma unroll
        for (int rt=0;rt<2;rt++){
            #pragma unroll
            for (int kt=0;kt<2;kt++){
                const float* pp = pebuf + (16*rt+lc)*68 + 32*kt + 8*lg;
                float4 lo = *(const float4*)pp, hi = *(const float4*)(pp+4);
                uint4 t4; t4.x=pk2(lo.x,lo.y); t4.y=pk2(lo.z,lo.w);
                t4.z=pk2(hi.x,hi.y); t4.w=pk2(hi.z,hi.w);
                short8 bv = __builtin_bit_cast(short8, t4);
                dd[rt] = __builtin_amdgcn_mfma_f32_16x16x32_bf16(aw[kt], bv, dd[rt], 0,0,0);
            }
        }
        #pragma unroll
        for (int rt=0;rt<2;rt++){
            float o[4];
            #pragma unroll
            for (int q=0;q<4;q++){
                int ncol = 16*wv + 4*lg + q;
                o[q] = lrelu(dd[rt][q] + BIAf[ncol]);
            }
            uint2 u; u.x = pk2(o[0],o[1]); u.y = pk2(o[2],o[3]);
            *(uint2*)(abuf0 + ((16*rt+lc)*136 + 16*wv + 4*lg)*2) = u;
        }
    }
    VMCNT0; __syncthreads();

    auto layerA = [&](const unsigned char* Wb, const unsigned char* inb, unsigned char* outb,
                      int biaso, bool act){
        short8 aw[4]; f32x4 dd[2]; dd[0]=z; dd[1]=z;
        #pragma unroll
        for (int kt=0;kt<4;kt++)
            aw[kt] = *(const short8*)(Wb + ((16*wv+lc)*136 + 32*kt + 8*lg)*2);
        #pragma unroll
        for (int rt=0;rt<2;rt++){
            #pragma unroll
            for (int kt=0;kt<4;kt++){
                short8 bv = *(const short8*)(inb + ((16*rt+lc)*136 + 32*kt + 8*lg)*2);
                dd[rt] = __builtin_amdgcn_mfma_f32_16x16x32_bf16(aw[kt], bv, dd[rt], 0,0,0);
            }
        }
        #pragma unroll
        for (int rt=0;rt<2;rt++){
            float o[4];
            #pragma unroll
            for (int q=0;q<4;q++){
                int ncol = 16*wv + 4*lg + q;
                float v = dd[rt][q];
                if (biaso >= 0) v += BIAf[biaso + ncol];
                o[q] = act ? lrelu(v) : v;
            }
            uint2 u; u.x = pk2(o[0],o[1]); u.y = pk2(o[2],o[3]);
            *(uint2*)(outb + ((16*rt+lc)*136 + 16*wv + 4*lg)*2) = u;
        }
    };

    stage(OP3, W0, 34816); layerA(W1, abuf0, abuf1, 128, true);  VMCNT0; __syncthreads(); // g2
    stage(OS1, W1, 34816); layerA(W0, abuf1, abuf0, 256, false); VMCNT0; __syncthreads(); // P
    stage(OS2, W0, 34816); layerA(W1, abuf0, abuf1, -1, false);  VMCNT0; __syncthreads(); // A1

    // ---- h1 fragments (registers), per wave = batch wv ----
    stage(OS3, W1, 34816);  // skw3 chunk 0
    short8 hf[2][4];
    #pragma unroll
    for (int rtl=0;rtl<2;rtl++){
        #pragma unroll
        for (int kt=0;kt<4;kt++){
            short8 a1v = *(const short8*)(abuf1 + ((16*rtl+lc)*136 + 32*kt + 8*lg)*2);
            const float* cp = C1f + wv*128 + 32*kt + 8*lg;
            float4 c0 = *(const float4*)cp, c1v = *(const float4*)(cp+4);
            float h[8];
            #pragma unroll
            for (int e=0;e<8;e++) h[e] = bf2f(a1v[e]);
            h[0]+=c0.x; h[1]+=c0.y; h[2]+=c0.z; h[3]+=c0.w;
            h[4]+=c1v.x; h[5]+=c1v.y; h[6]+=c1v.z; h[7]+=c1v.w;
            #pragma unroll
            for (int e=0;e<8;e++) h[e] = lrelu(h[e]);
            uint4 t4; t4.x=pk2(h[0],h[1]); t4.y=pk2(h[2],h[3]);
            t4.z=pk2(h[4],h[5]); t4.w=pk2(h[6],h[7]);
            hf[rtl][kt] = __builtin_bit_cast(short8, t4);
        }
    }
    __syncthreads();   // all abuf1 reads done before h2b writes alias it

    // ---- layer2 (swapped): h2^T written k-contig ----
    #pragma unroll
    for (int n2t=0;n2t<8;n2t++){
        short8 aw[4];
        #pragma unroll
        for (int kt=0;kt<4;kt++)
            aw[kt] = *(const short8*)(W0 + ((16*n2t+lc)*136 + 32*kt + 8*lg)*2);
        f32x4 d2[2]; d2[0]=z; d2[1]=z;
        #pragma unroll
        for (int rtl=0;rtl<2;rtl++){
            #pragma unroll
            for (int kt=0;kt<4;kt++)
                d2[rtl] = __builtin_amdgcn_mfma_f32_16x16x32_bf16(aw[kt], hf[rtl][kt], d2[rtl], 0,0,0);
        }
        #pragma unroll
        for (int rtl=0;rtl<2;rtl++){
            float o[4];
            #pragma unroll
            for (int q=0;q<4;q++){
                int n2 = 16*n2t + 4*lg + q;
                o[q] = lrelu(d2[rtl][q] + BIAf[384 + n2]);
            }
            uint2 u; u.x = pk2(o[0],o[1]); u.y = pk2(o[2],o[3]);
            *(uint2*)(h2b + ((32*wv+16*rtl+lc)*136 + 16*n2t + 4*lg)*2) = u;
        }
    }
    VMCNT0; __syncthreads();   // h2 complete + skw3 ch0 landed

    // ---- layer3 + fused softmax-dot ----
    const int q4 = wv & 3;
    const int nhalf = (wv >> 2) * 4;
    short8 h2f[4][4];
    #pragma unroll
    for (int rtl=0;rtl<4;rtl++){
        #pragma unroll
        for (int kt=0;kt<4;kt++)
            h2f[rtl][kt] = *(const short8*)(h2b + ((16*(4*q4+rtl)+lc)*136 + 32*kt + 8*lg)*2);
    }
    float SS[16], WW[16];
    #pragma unroll
    for (int i=0;i<16;i++){ SS[i]=0.f; WW[i]=0.f; }
    const float* selp = ws + WS_SEL + (2*q4)*K;

    for (int ch=0; ch<4; ch++){
        const unsigned char* Wb = (ch & 1) ? W0 : W1;
        if (ch < 3) stage(OS3 + (ch+1)*17408, (ch & 1) ? W1 : W0, 34816);
        #pragma unroll
        for (int nl=0; nl<4; nl++){
            int n3t = 8*ch + nhalf + nl;
            int loc = 16*(nhalf+nl) + lc;
            short8 bw[4];
            #pragma unroll
            for (int kt=0;kt<4;kt++)
                bw[kt] = *(const short8*)(Wb + (loc*136 + 32*kt + 8*lg)*2);
            f32x4 d3[4];
            #pragma unroll
            for (int rtl=0;rtl<4;rtl++){
                d3[rtl] = z;
                #pragma unroll
                for (int kt=0;kt<4;kt++)
                    d3[rtl] = __builtin_amdgcn_mfma_f32_16x16x32_bf16(h2f[rtl][kt], bw[kt], d3[rtl], 0,0,0);
            }
            int n3 = 16*n3t + lc;
            float b3v = BIAf[512 + n3];
            float s0 = selp[n3], s1 = selp[K + n3];
            #pragma unroll
            for (int rtl=0;rtl<4;rtl++){
                float sv = (rtl < 2) ? s0 : s1;
                #pragma unroll
                for (int q=0;q<4;q++){
                    float e = __expf(d3[rtl][q] + b3v);
                    SS[rtl*4+q] += e;
                    WW[rtl*4+q] = fmaf(e, sv, WW[rtl*4+q]);
                }
            }
        }
        VMCNT0; __syncthreads();
    }

    // allreduce partial sums across the 16-lane col groups
    #pragma unroll
    for (int i=0;i<16;i++){
        #pragma unroll
        for (int off=1; off<16; off<<=1){
            SS[i] += __shfl_xor(SS[i], off, 64);
            WW[i] += __shfl_xor(WW[i], off, 64);
        }
    }
    float Ssel=0.f, Wsel=0.f;
    #pragma unroll
    for (int i=0;i<16;i++){ if (lc==i){ Ssel=SS[i]; Wsel=WW[i]; } }
    int row = 16*(4*q4 + (lc>>2)) + 4*lg + (lc&3);
    if (wv < 4){
        PART[row] = Ssel; PART[256+row] = Wsel;
    }
    __syncthreads();
    if (wv >= 4){
        float Stot = Ssel + PART[row];
        float Wtot = Wsel + PART[256+row];
        int b = row >> 5, tl = row & 31, t = t0 + tl;
        float coord = (t + 0.5f)*(1.0f/256.0f) - 0.5f;
        float fi = floorf(coord); float frac = coord - fi;
        int i0 = (int)fi; int i1 = i0 + 1;
        i0 = min(max(i0,0),NFRM-1); i1 = min(max(i1,0),NFRM-1);
        float e0 = ws[WS_ENV8 + b*NFRM + i0], e1 = ws[WS_ENV8 + b*NFRM + i1];
        float envv = e0*(1.0f-frac) + e1*frac;
        out[b*T_SAMP + t] = (Wtot/Stot) * envv * ws[WS_VAL+b];
    }
}

// ---------------- fallback fp32 synth (round-1, known good) ----------------
__global__ __launch_bounds__(512) void synth_kernel(
    const float* __restrict__ pos_w1, const float* __restrict__ pos_b1,
    const float* __restrict__ pos_w2, const float* __restrict__ pos_b2,
    const float* __restrict__ pos_w3, const float* __restrict__ pos_b3,
    const float* __restrict__ sk_w1,
    const float* __restrict__ sk_w2, const float* __restrict__ sk_b2,
    const float* __restrict__ sk_w3, const float* __restrict__ sk_b3,
    const float* __restrict__ ws, float* __restrict__ out)
{
    __shared__ __align__(16) float wbuf[D*D];
    __shared__ __align__(16) float h1T[D*HSTR];
    __shared__ __align__(16) float h2T[D*HSTR];
    __shared__ __align__(16) float peT[33*9];
    __shared__ __align__(16) float sA[D*9];
    __shared__ __align__(16) float sB[D*9];
    __shared__ float c1l[B*D];

    int tid = threadIdx.x;
    int t0 = blockIdx.x * TB;

    for (int i=tid;i<B*D;i+=512) c1l[i] = ws[WS_C1+i];
    for (int i=tid;i<33*D;i+=512) wbuf[i] = pos_w1[i];
    for (int i=tid;i<33*TB;i+=512){
        int j = i>>3, r = i&7;
        float pf = (float)(-1.0 + 2.0*(double)(t0+r)/32767.0);
        float v;
        if (j == 0) v = pf;
        else if (j <= 16) v = sinf(pf * ((float)M_PI * (float)(1<<(j-1))));
        else v = cosf(pf * ((float)M_PI * (float)(1<<(j-17))));
        peT[j*9+r] = v;
    }
    __syncthreads();

    const int c  = tid & 127;
    const int rg = tid >> 7;
    {
        int r0 = rg*2;
        float a0 = pos_b1[c], a1 = a0;
        for (int j=0;j<33;j++){
            float w = wbuf[j*D+c];
            a0 = fmaf(peT[j*9+r0],   w, a0);
            a1 = fmaf(peT[j*9+r0+1], w, a1);
        }
        sA[c*9+r0]   = lrelu(a0);
        sA[c*9+r0+1] = lrelu(a1);
    }
    __syncthreads();
    for (int i=tid;i<D*D;i+=512) wbuf[i] = pos_w2[i];
    __syncthreads();
    {
        int r0 = rg*2;
        float a0 = pos_b2[c], a1 = a0;
        #pragma unroll 4
        for (int j=0;j<D;j++){
            float w = wbuf[j*D+c];
            a0 = fmaf(sA[j*9+r0],   w, a0);
            a1 = fmaf(sA[j*9+r0+1], w, a1);
        }
        sB[c*9+r0]   = lrelu(a0);
        sB[c*9+r0+1] = lrelu(a1);
    }
    __syncthreads();
    for (int i=tid;i<D*D;i+=512) wbuf[i] = pos_w3[i];
    __syncthreads();
    {
        int r0 = rg*2;
        float a0 = pos_b3[c], a1 = a0;
        #pragma unroll 4
        for (int j=0;j<D;j++){
            float w = wbuf[j*D+c];
            a0 = fmaf(sB[j*9+r0],   w, a0);
            a1 = fmaf(sB[j*9+r0+1], w, a1);
        }
        sA[c*9+r0]   = a0;
        sA[c*9+r0+1] = a1;
    }
    __syncthreads();
    for (int i=tid;i<D*D;i+=512) wbuf[i] = sk_w1[i];
    __syncthreads();
    {
        int r0 = rg*2;
        float a0 = 0.f, a1 = 0.f;
        #pragma unroll 4
        for (int j=0;j<D;j++){
            float w = wbuf[j*D+c];
            a0 = fmaf(sA[j*9+r0],   w, a0);
            a1 = fmaf(sA[j*9+r0+1], w, a1);
        }
        sB[c*9+r0]   = a0;
        sB[c*9+r0+1] = a1;
    }
    __syncthreads();
    {
        int r0 = rg*16;
        for (int r=r0;r<r0+16;r++){
            int b = r>>3, ti = r&7;
            h1T[c*HSTR + r] = lrelu(sB[c*9+ti] + c1l[b*D+c]);
        }
    }
    __syncthreads();
    for (int i=tid;i<D*D;i+=512) wbuf[i] = sk_w2[i];
    __syncthreads();
    {
        int r0 = rg*16;
        float acc[16];
        float bv = sk_b2[c];
        #pragma unroll
        for (int i=0;i<16;i++) acc[i]=bv;
        #pragma unroll 2
        for (int j=0;j<D;j++){
            float w = wbuf[j*D+c];
            const float4* hp = (const float4*)&h1T[j*HSTR + r0];
            #pragma unroll
            for (int q=0;q<4;q++){
                float4 h4 = hp[q];
                acc[4*q+0] = fmaf(h4.x, w, acc[4*q+0]);
                acc[4*q+1] = fmaf(h4.y, w, acc[4*q+1]);
                acc[4*q+2] = fmaf(h4.z, w, acc[4*q+2]);
                acc[4*q+3] = fmaf(h4.w, w, acc[4*q+3]);
            }
        }
        #pragma unroll
        for (int i=0;i<16;i++) h2T[c*HSTR + r0 + i] = lrelu(acc[i]);
    }
    __syncthreads();
    const int kc = tid & 63;
    const int wv = tid >> 6;
    float S[8], W[8];
    #pragma unroll
    for (int i=0;i<8;i++){ S[i]=0.f; W[i]=0.f; }
    for (int kt=0;kt<8;kt++){
        for (int i=tid;i<D*64;i+=512){
            int j = i>>6, k2 = i&63;
            wbuf[i] = sk_w3[j*K + kt*64 + k2];
        }
        __syncthreads();
        float acc[8];
        float bv = sk_b3[kt*64+kc];
        #pragma unroll
        for (int i=0;i<8;i++) acc[i]=bv;
        #pragma unroll 2
        for (int j=0;j<D;j++){
            float w = wbuf[j*64+kc];
            const float4* hp = (const float4*)&h2T[j*HSTR + wv*8];
            #pragma unroll
            for (int q=0;q<2;q++){
                float4 h4 = hp[q];
                acc[4*q+0] = fmaf(h4.x, w, acc[4*q+0]);
                acc[4*q+1] = fmaf(h4.y, w, acc[4*q+1]);
                acc[4*q+2] = fmaf(h4.z, w, acc[4*q+2]);
                acc[4*q+3] = fmaf(h4.w, w, acc[4*q+3]);
            }
        }
        float selv = ws[WS_SEL + wv*K + kt*64 + kc];
        #pragma unroll
        for (int i=0;i<8;i++){
            float e = expf(acc[i]);
            S[i] += e;
            W[i] = fmaf(e, selv, W[i]);
        }
        __syncthreads();
    }
    #pragma unroll
    for (int i=0;i<8;i++){
        #pragma unroll
        for (int off=32; off>0; off>>=1){
            S[i] += __shfl_xor(S[i], off, 64);
            W[i] += __shfl_xor(W[i], off, 64);
        }
    }
    int lane = tid & 63;
    if (lane < 8){
        int i = lane;
        int t = t0 + i;
        float coord = (t + 0.5f)*(1.0f/256.0f) - 0.5f;
        float fi = floorf(coord);
        float frac = coord - fi;
        int i0 = (int)fi;
        int i1 = i0 + 1;
        i0 = min(max(i0,0),NFRM-1);
        i1 = min(max(i1,0),NFRM-1);
        float e0 = ws[WS_ENV8 + wv*NFRM + i0];
        float e1 = ws[WS_ENV8 + wv*NFRM + i1];
        float envv = e0*(1.0f-frac) + e1*frac;
        out[wv*T_SAMP + t] = (W[i]/S[i]) * envv * ws[WS_VAL+wv];
    }
}

extern "C" void kernel_launch(void* const* d_in, const int* in_sizes, int n_in,
                              void* d_out, int out_size, void* d_ws, size_t ws_size,
                              hipStream_t stream)
{
    (void)in_sizes; (void)n_in; (void)out_size;
    const float* x       = (const float*)d_in[0];
    const float* wt      = (const float*)d_in[1];
    const float* tc_w1   = (const float*)d_in[2];
    const float* tc_b1   = (const float*)d_in[3];
    const float* tc_w2   = (const float*)d_in[4];
    const float* tc_b2   = (const float*)d_in[5];
    const float* tc_w3   = (const float*)d_in[6];
    const float* tc_b3   = (const float*)d_in[7];
    const float* env_w1  = (const float*)d_in[8];
    const float* env_b1  = (const float*)d_in[9];
    const float* env_w2  = (const float*)d_in[10];
    const float* env_b2  = (const float*)d_in[11];
    const float* env_w3  = (const float*)d_in[12];
    const float* env_b3  = (const float*)d_in[13];
    const float* pos_w1  = (const float*)d_in[14];
    const float* pos_b1  = (const float*)d_in[15];
    const float* pos_w2  = (const float*)d_in[16];
    const float* pos_b2  = (const float*)d_in[17];
    const float* pos_w3  = (const float*)d_in[18];
    const float* pos_b3  = (const float*)d_in[19];
    const float* sk_w1   = (const float*)d_in[20];
    const float* sk_b1   = (const float*)d_in[21];
    const float* sk_w2   = (const float*)d_in[22];
    const float* sk_b2   = (const float*)d_in[23];
    const float* sk_w3   = (const float*)d_in[24];
    const float* sk_b3   = (const float*)d_in[25];
    float* ws  = (float*)d_ws;
    float* out = (float*)d_out;

    bool fast = ws_size >= (size_t)WS_NEED;

    hipLaunchKernelGGL(setup_kernel, dim3(fast ? 1 + (WTOT+255)/256 : 1), dim3(256), 0, stream,
        x, wt, tc_w1, tc_b1, tc_w2, tc_b2, tc_w3, tc_b3,
        env_w1, env_b1, env_w2, env_b2, env_w3, env_b3,
        sk_w1, sk_b1, pos_w1, pos_w2, pos_w3, sk_w2, sk_w3, ws);

    if (fast){
        hipLaunchKernelGGL(synth_fast, dim3(T_SAMP/32), dim3(512), 0, stream,
            pos_b1, pos_b2, pos_b3, sk_b2, sk_b3, ws, out);
    } else {
        hipLaunchKernelGGL(synth_kernel, dim3(T_SAMP/TB), dim3(512), 0, stream,
            pos_w1, pos_b1, pos_w2, pos_b2, pos_w3, pos_b3,
            sk_w1, sk_w2, sk_b2, sk_w3, sk_b3, ws, out);
    }
}